// Round 8
// baseline (216.652 us; speedup 1.0000x reference)
//
#include <hip/hip_runtime.h>
#include <math.h>

// ---------------------------------------------------------------------------
// Fused 11-layer funnel MLP, round 8: 2-wave producer/consumer pairs.
// Wave A: L0..L3 weights in VGPRs (82 K=16 A-frags = 164 VGPR), chains
//   x -> h4 entirely in-register via mfma 16x16x16 (C/D layout == B16-operand
//   layout, verified r7), writes h4 to a small LDS edge (ping-pong).
// Wave B: L4..L10 weights in VGPRs (85 frags = 170), reads h4 frags, chains
//   to the sigmoid output in-register.
// 128-thread blocks (one pair) -> barrier scope is 2 balanced waves
// (164 vs 170 mfma16 per 32-row group). 1024 blocks = 4/CU, 16 KB LDS each.
// Weights load global->registers directly (no staging, no bootstrap barriers).
// Bias via weight pad columns + 1.0-generator rows (verified r3-r7).
// ---------------------------------------------------------------------------

using s16x4 = __attribute__((ext_vector_type(4))) short;
using bf16x8 = __attribute__((ext_vector_type(8))) short;
using f32x4 = __attribute__((ext_vector_type(4))) float;
using u32x2 = __attribute__((ext_vector_type(2))) unsigned;
typedef __bf16 bf16x2_t __attribute__((ext_vector_type(2)));

namespace {
constexpr int G = 32;            // rows per group (2 x 16-row tiles)
constexpr int BLOCKS = 1024;     // 4 blocks/CU
// LDS: h4 edge, [2 parity][2 tiles][8 windows][256 shorts] = 8192 shorts
constexpr int LDS_BYTES = 8192 * 2;
}

__device__ __forceinline__ unsigned short f2bf(float f) {
    unsigned u = __float_as_uint(f);
    u += 0x7fffu + ((u >> 16) & 1u);
    return (unsigned short)(u >> 16);
}

__device__ __forceinline__ unsigned pk2(float a, float b) {
#if defined(__HIP_DEVICE_COMPILE__) && __has_builtin(__builtin_amdgcn_cvt_pk_bf16_f32)
    return __builtin_bit_cast(unsigned, __builtin_amdgcn_cvt_pk_bf16_f32(a, b));
#else
    bf16x2_t c; c[0] = (__bf16)a; c[1] = (__bf16)b;
    return __builtin_bit_cast(unsigned, c);
#endif
}

__device__ __forceinline__ s16x4 pack4(float a, float b, float c, float d) {
    u32x2 p; p[0] = pk2(a, b); p[1] = pk2(c, d);
    return __builtin_bit_cast(s16x4, p);
}

// ReLU + pack a C-tile accumulator into a K=16 B-operand fragment.
__device__ __forceinline__ s16x4 pr16(f32x4 a) {
    return pack4(fmaxf(a[0], 0.f), fmaxf(a[1], 0.f), fmaxf(a[2], 0.f), fmaxf(a[3], 0.f));
}

__device__ __forceinline__ s16x4 lo8(bf16x8 v) { return __builtin_shufflevector(v, v, 0, 1, 2, 3); }
__device__ __forceinline__ bf16x8 cat4(s16x4 a, s16x4 b) { return __builtin_shufflevector(a, b, 0, 1, 2, 3, 4, 5, 6, 7); }

// 16x16x16 bf16 MFMA (exact zero-padded K=32 fallback; both verified r7).
__device__ __forceinline__ f32x4 mfma16(s16x4 a, s16x4 b, f32x4 c) {
#if defined(__HIP_DEVICE_COMPILE__) && __has_builtin(__builtin_amdgcn_mfma_f32_16x16x16bf16_1k)
    return __builtin_amdgcn_mfma_f32_16x16x16bf16_1k(a, b, c, 0, 0, 0);
#else
    const s16x4 z = {0, 0, 0, 0};
    return __builtin_amdgcn_mfma_f32_16x16x32_bf16(cat4(a, z), cat4(b, z), c, 0, 0, 0);
#endif
}

__device__ __forceinline__ float4 ld4(const float* p) {
    float4 t; __builtin_memcpy(&t, p, 16); return t;
}

// One K=16 A-frag of layer (INl,OUTl) direct from global, with bias columns
// (hi at k=IN, lo at k=IN+1 if BLO) and NGEN 1.0-generator pad rows.
template <int INl, int OUTl, bool BLO, int NGEN>
__device__ __forceinline__ s16x4 wfrag(const float* __restrict__ W,
                                       const float* __restrict__ Bv,
                                       int m, int k0) {
    float v0, v1, v2, v3;
    if (m < OUTl && k0 + 3 < INl) {
        float4 t = ld4(W + m * INl + k0);
        v0 = t.x; v1 = t.y; v2 = t.z; v3 = t.w;
    } else {
        float vv[4];
#pragma unroll
        for (int j = 0; j < 4; ++j) {
            const int k = k0 + j;
            float xv = 0.f;
            if (m < OUTl) {
                if (k < INl) xv = W[m * INl + k];
                else if (k == INl) xv = Bv[m];
                else if (BLO && k == INl + 1) {
                    float hf = __builtin_bit_cast(float, (unsigned)f2bf(Bv[m]) << 16);
                    xv = Bv[m] - hf;
                }
            } else if (NGEN > 0 && m < OUTl + NGEN && k == INl) {
                xv = 1.f;
            }
            vv[j] = xv;
        }
        v0 = vv[0]; v1 = vv[1]; v2 = vv[2]; v3 = vv[3];
    }
    return pack4(v0, v1, v2, v3);
}

// Load a whole layer's K=16 A-frags into a register array.
template <int INl, int OUTl, int NKT, int NMT, bool BLO, int NGEN>
__device__ __forceinline__ void load_layer(const float* __restrict__ W,
                                           const float* __restrict__ Bv,
                                           s16x4 (&dst)[NKT * NMT], int col, int quad) {
#pragma unroll
    for (int mt = 0; mt < NMT; ++mt)
#pragma unroll
        for (int kt = 0; kt < NKT; ++kt)
            dst[mt * NKT + kt] = wfrag<INl, OUTl, BLO, NGEN>(W, Bv, mt * 16 + col, kt * 16 + quad * 4);
}

// One chained layer: B16-frags in -> ReLU'd B16-frags out (all in registers).
template <int NKT, int NMT>
__device__ __forceinline__ void layerc(const s16x4 (&w)[NKT * NMT],
                                       const s16x4 (&in)[NKT], s16x4 (&out)[NMT]) {
#pragma unroll
    for (int mt = 0; mt < NMT; ++mt) {
        f32x4 acc = {0.f, 0.f, 0.f, 0.f};
#pragma unroll
        for (int kt = 0; kt < NKT; ++kt)
            acc = mfma16(w[mt * NKT + kt], in[kt], acc);
        out[mt] = pr16(acc);
    }
}

// Lane (col,quad) fetches x[row=t*16+col][quad*4..+3] (quad3: k=12..14 + 1.0).
__device__ __forceinline__ void fetch_x2(const float* __restrict__ x, int row0,
                                         int col, int quad, float4 (&xv)[2]) {
#pragma unroll
    for (int t = 0; t < 2; ++t) {
        const float* xr = x + (long)(row0 + t * 16 + col) * 15;
        if (quad < 3) {
            xv[t] = ld4(xr + quad * 4);
        } else {
            float4 u = ld4(xr + 11);
            xv[t] = make_float4(u.y, u.z, u.w, 1.f);
        }
    }
}

extern "C" __global__ void __launch_bounds__(128, 2)
mlp_pair(const float* __restrict__ x,
         const float* __restrict__ W0,  const float* __restrict__ B0,
         const float* __restrict__ W1,  const float* __restrict__ B1,
         const float* __restrict__ W2,  const float* __restrict__ B2,
         const float* __restrict__ W3,  const float* __restrict__ B3,
         const float* __restrict__ W4,  const float* __restrict__ B4,
         const float* __restrict__ W5,  const float* __restrict__ B5,
         const float* __restrict__ W6,  const float* __restrict__ B6,
         const float* __restrict__ W7,  const float* __restrict__ B7,
         const float* __restrict__ W8,  const float* __restrict__ B8,
         const float* __restrict__ W9,  const float* __restrict__ B9,
         const float* __restrict__ W10, const float* __restrict__ B10,
         float* __restrict__ out, int ng) {
    extern __shared__ __align__(16) short smem[];   // h4 edge: 2 x 4096 shorts
    const int tid  = threadIdx.x;
    const int lane = tid & 63;
    const int col  = lane & 15;
    const int quad = lane >> 4;
    const int sw   = __builtin_amdgcn_readfirstlane(tid >> 6);   // 0 = A, 1 = B
    const int eo   = quad * 64 + col * 4;                        // lane slot in a window
    const int gbase = blockIdx.x * ng;

    if (sw == 0) {
        // ---------------- wave A: x -> L0 -> L1 -> L2 -> L3 -> edge ----------
        s16x4 wA0[2];  load_layer<15, 30, 1, 2, false, 2>(W0, B0, wA0, col, quad);
        s16x4 wA1[8];  load_layer<30, 60, 2, 4, true,  2>(W1, B1, wA1, col, quad);
        s16x4 wA2[24]; load_layer<60, 90, 4, 6, true,  2>(W2, B2, wA2, col, quad);
        s16x4 wA3[48]; load_layer<90, 120, 6, 8, true, 2>(W3, B3, wA3, col, quad);

        float4 xf[2];
        if (ng > 0) fetch_x2(x, gbase * G, col, quad, xf);

        for (int n = 0; n <= ng; ++n) {
            if (n < ng) {
                s16x4 xq[2];
                xq[0] = pack4(xf[0].x, xf[0].y, xf[0].z, xf[0].w);
                xq[1] = pack4(xf[1].x, xf[1].y, xf[1].z, xf[1].w);
                if (n + 1 < ng) fetch_x2(x, (gbase + n + 1) * G, col, quad, xf);

                short* ep = smem + (n & 1) * 4096;
#pragma unroll
                for (int t = 0; t < 2; ++t) {
                    s16x4 xin[1] = {xq[t]};
                    s16x4 h1[2], h2[4], h3[6];
                    layerc<1, 2>(wA0, xin, h1);
                    layerc<2, 4>(wA1, h1, h2);
                    layerc<4, 6>(wA2, h2, h3);
                    // L3 -> edge (C-tile == B16-frag for window mt; 8B store)
#pragma unroll
                    for (int mt = 0; mt < 8; ++mt) {
                        f32x4 acc = {0.f, 0.f, 0.f, 0.f};
#pragma unroll
                        for (int kt = 0; kt < 6; ++kt)
                            acc = mfma16(wA3[mt * 6 + kt], h3[kt], acc);
                        *(s16x4*)(ep + t * 2048 + mt * 256 + eo) = pr16(acc);
                    }
                }
            }
            __syncthreads();
        }
    } else {
        // ---------------- wave B: edge -> L4..L9 -> L10 + sigmoid ------------
        s16x4 wB4[48]; load_layer<120, 90, 8, 6, true, 2>(W4, B4, wB4, col, quad);
        s16x4 wB5[24]; load_layer<90, 60, 6, 4, true,  2>(W5, B5, wB5, col, quad);
        s16x4 wB6[8];  load_layer<60, 30, 4, 2, true,  2>(W6, B6, wB6, col, quad);
        s16x4 wB7[2];  load_layer<30, 15, 2, 1, true,  1>(W7, B7, wB7, col, quad);
        s16x4 wB8[1];  load_layer<15, 10, 1, 1, false, 2>(W8, B8, wB8, col, quad);
        s16x4 wB9[1];  load_layer<10, 5, 1, 1, true,  2>(W9, B9, wB9, col, quad);
        s16x4 wB10[1]; load_layer<5, 1, 1, 1, true,  0>(W10, B10, wB10, col, quad);

        for (int n = 0; n <= ng; ++n) {
            if (n >= 1) {
                const int g = n - 1;
                const short* ep = smem + (g & 1) * 4096;
#pragma unroll
                for (int t = 0; t < 2; ++t) {
                    s16x4 h4[8];
#pragma unroll
                    for (int mt = 0; mt < 8; ++mt)
                        h4[mt] = *(const s16x4*)(ep + t * 2048 + mt * 256 + eo);
                    s16x4 h5[6], h6[4], h7[2], h8[1], h9[1], h10[1];
                    layerc<8, 6>(wB4, h4, h5);
                    layerc<6, 4>(wB5, h5, h6);
                    layerc<4, 2>(wB6, h6, h7);
                    layerc<2, 1>(wB7, h7, h8);
                    layerc<1, 1>(wB8, h8, h9);
                    layerc<1, 1>(wB9, h9, h10);
                    f32x4 oz = {0.f, 0.f, 0.f, 0.f};
                    oz = mfma16(wB10[0], h10[0], oz);
                    if (quad == 0)
                        out[(gbase + g) * G + t * 16 + col] = 1.f / (1.f + __expf(-oz[0]));
                }
            }
            __syncthreads();
        }
    }
}

extern "C" void kernel_launch(void* const* d_in, const int* in_sizes, int n_in,
                              void* d_out, int out_size, void* d_ws, size_t ws_size,
                              hipStream_t stream) {
    (void)n_in; (void)d_ws; (void)ws_size; (void)out_size;
    const float* x = (const float*)d_in[0];
    const float* W[11];
    const float* B[11];
    for (int i = 0; i < 11; ++i) {
        W[i] = (const float*)d_in[1 + 2 * i];
        B[i] = (const float*)d_in[2 + 2 * i];
    }
    const int nrows = in_sizes[0] / 15;
    const int ng    = nrows / (BLOCKS * G);   // 524288 / (1024*32) = 16

    mlp_pair<<<dim3(BLOCKS), dim3(128), LDS_BYTES, stream>>>(
        x,
        W[0], B[0], W[1], B[1], W[2], B[2], W[3], B[3], W[4], B[4],
        W[5], B[5], W[6], B[6], W[7], B[7], W[8], B[8], W[9], B[9],
        W[10], B[10],
        (float*)d_out, ng);
}